// Round 13
// baseline (137.882 us; speedup 1.0000x reference)
//
#include <hip/hip_runtime.h>
#include <hip/hip_bf16.h>
#include <math.h>

// ---------------------------------------------------------------------------
// SelfAttention2d: x(8,256,32,32) -> GN(8 groups) -> qkv(768x256 GEMM)
//   -> 32 heads, d=8, attention over t=1024 -> out(256x256 GEMM) + bias + x
// Round 13: LDS-free GEMMs. With B t-major [t][c] and W [o][c], BOTH mfma
// fragments are verbatim 16B row-chunks (lane l15 = row, quad = k-chunk), so
// the LDS stage + swizzle + 2 barriers/k-iter was pure overhead. Direct
// global fragment loads, zero LDS, zero barriers, unrolled k-loop.
// Attention reverted to R10's measured-best kernel (K+V in LDS, 1024 blocks).
// ---------------------------------------------------------------------------

#define NBATCH 8
#define C 256
#define HW 1024
#define NHEAD 32
#define HDIM 8

typedef __bf16 bf16x8 __attribute__((ext_vector_type(8)));
typedef __bf16 bf16x4 __attribute__((ext_vector_type(4)));
typedef _Float16 f16x8 __attribute__((ext_vector_type(8)));
typedef _Float16 f16x4 __attribute__((ext_vector_type(4)));
typedef float floatx4 __attribute__((ext_vector_type(4)));
typedef float floatx16 __attribute__((ext_vector_type(16)));

#if __has_builtin(__builtin_amdgcn_exp2f)
#define EXP2F(x) __builtin_amdgcn_exp2f(x)
#else
#define EXP2F(x) exp2f(x)
#endif

#define SCALE_LOG2E 0.51013249662f   // (1/sqrt(8)) * log2(e)

// ---- GN stats (blocks 0..511) + weight cvt (blocks 512..767) ---------------
__global__ __launch_bounds__(256) void gn_stats_cvt_kernel(
    const float* __restrict__ x, float* __restrict__ stats,
    const float* __restrict__ qw, const float* __restrict__ ow,
    __bf16* __restrict__ wq, __bf16* __restrict__ wo)
{
    int blk = blockIdx.x;
    int tid = threadIdx.x;
    if (blk >= 512) {                            // weight convert
        int id = (blk - 512) * 256 + tid;        // 0..65535, 4 floats each
        float4 v;
        __bf16* dst;
        if (id < 49152) { v = *(const float4*)&qw[id * 4]; dst = wq + id * 4; }
        else { v = *(const float4*)&ow[(id - 49152) * 4]; dst = wo + (id - 49152) * 4; }
        bf16x4 o = { (__bf16)v.x, (__bf16)v.y, (__bf16)v.z, (__bf16)v.w };
        *(bf16x4*)dst = o;
        return;
    }
    int part = blk & 7, ng = blk >> 3;
    const float4* xv = (const float4*)(x + ((size_t)ng * 32 + part * 4) * HW);
    float s = 0.f, ss = 0.f;
#pragma unroll
    for (int i = 0; i < 4; ++i) {
        float4 v = xv[tid + i * 256];
        s  += v.x + v.y + v.z + v.w;
        ss += v.x*v.x + v.y*v.y + v.z*v.z + v.w*v.w;
    }
#pragma unroll
    for (int o = 32; o; o >>= 1) { s += __shfl_xor(s, o); ss += __shfl_xor(ss, o); }
    __shared__ float rs[4], rss[4];
    int wave = tid >> 6, lane = tid & 63;
    if (lane == 0) { rs[wave] = s; rss[wave] = ss; }
    __syncthreads();
    if (tid == 0) {
        stats[blk * 2]     = rs[0] + rs[1] + rs[2] + rs[3];
        stats[blk * 2 + 1] = rss[0] + rss[1] + rss[2] + rss[3];
    }
}

// ---- GN apply -> xnT bf16 [n][t][c]: 256 blocks = (n,g,chunk of 256 t) -----
__global__ __launch_bounds__(256) void gn_apply_kernel(
    const float* __restrict__ x, const float* __restrict__ w,
    const float* __restrict__ b, const float* __restrict__ stats,
    __bf16* __restrict__ xnT)
{
    int blk = blockIdx.x;
    int chunk = blk & 3, ng = blk >> 2;
    int n = ng >> 3, g = ng & 7;
    float s = 0.f, ss = 0.f;
#pragma unroll
    for (int p = 0; p < 8; ++p) {            // uniform -> scalar loads
        s  += stats[(ng * 8 + p) * 2];
        ss += stats[(ng * 8 + p) * 2 + 1];
    }
    const float invN = 1.0f / 32768.0f;
    float mean = s * invN;
    float var  = ss * invN - mean * mean;
    float rstd = rsqrtf(var + 1e-5f);
    const float* xp = x + ((size_t)ng * 32) * HW;
    int tid = threadIdx.x, t0 = chunk * 256;
    __shared__ __bf16 Lt[32][257];
#pragma unroll 8
    for (int c = 0; c < 32; ++c) {
        float wc = w[g * 32 + c] * rstd;
        float bc = b[g * 32 + c] - mean * wc;
        float v = xp[(size_t)c * HW + t0 + tid];
        Lt[c][tid] = (__bf16)(v * wc + bc);
    }
    __syncthreads();
    __bf16* xo = xnT + (size_t)n * HW * C + g * 32;
#pragma unroll
    for (int q = 0; q < 4; ++q) {
        bf16x8 o;
#pragma unroll
        for (int e = 0; e < 8; ++e) o[e] = Lt[q * 8 + e][tid];
        *(bf16x8*)&xo[(size_t)(t0 + tid) * C + q * 8] = o;
    }
}

// ---- qkv GEMM, LDS-free: 64x128 tile, 4 waves of 32x64 ---------------------
// A-frag = W row chunk (lane l15 = o-row, quad = k-chunk), B-frag = xnT row
// chunk (lane l15 = t-row). No LDS, no barriers; rows fully consumed across
// the unrolled k-loop -> L1-resident. Epilogue scatter unchanged:
//   o<256 -> Qf f16 [n][h][t][8] *scale*log2e; o<512 -> Kf; else Vb bf16 [c][t]
__global__ __launch_bounds__(256) void gemm_qkv_kernel(
    const __bf16* __restrict__ W, const __bf16* __restrict__ Ball,
    const float* __restrict__ bias, _Float16* __restrict__ Qf,
    _Float16* __restrict__ Kf, __bf16* __restrict__ Vbf)
{
    int n = blockIdx.z;
    const __bf16* B = Ball + (size_t)n * HW * C;
    int om0 = blockIdx.y * 64, t0 = blockIdx.x * 128;
    int tid = threadIdx.x, lane = tid & 63, wave = tid >> 6;
    int l15 = lane & 15, quad = lane >> 4;
    int wm = (wave & 1) * 32, wn = (wave >> 1) * 64;
    const __bf16* ap0 = &W[(size_t)(om0 + wm + l15) * C + quad * 8];
    const __bf16* ap1 = ap0 + (size_t)16 * C;
    const __bf16* bp0 = &B[(size_t)(t0 + wn + l15) * C + quad * 8];
    const __bf16* bp1 = bp0 + (size_t)16 * C;
    const __bf16* bp2 = bp0 + (size_t)32 * C;
    const __bf16* bp3 = bp0 + (size_t)48 * C;
    floatx4 acc[2][4] = {};
#pragma unroll
    for (int k = 0; k < 8; ++k) {
        int c0 = k * 32;
        bf16x8 af0 = *(const bf16x8*)&ap0[c0];
        bf16x8 af1 = *(const bf16x8*)&ap1[c0];
        bf16x8 bf0 = *(const bf16x8*)&bp0[c0];
        bf16x8 bf1 = *(const bf16x8*)&bp1[c0];
        bf16x8 bf2 = *(const bf16x8*)&bp2[c0];
        bf16x8 bf3 = *(const bf16x8*)&bp3[c0];
        acc[0][0] = __builtin_amdgcn_mfma_f32_16x16x32_bf16(af0, bf0, acc[0][0], 0, 0, 0);
        acc[0][1] = __builtin_amdgcn_mfma_f32_16x16x32_bf16(af0, bf1, acc[0][1], 0, 0, 0);
        acc[0][2] = __builtin_amdgcn_mfma_f32_16x16x32_bf16(af0, bf2, acc[0][2], 0, 0, 0);
        acc[0][3] = __builtin_amdgcn_mfma_f32_16x16x32_bf16(af0, bf3, acc[0][3], 0, 0, 0);
        acc[1][0] = __builtin_amdgcn_mfma_f32_16x16x32_bf16(af1, bf0, acc[1][0], 0, 0, 0);
        acc[1][1] = __builtin_amdgcn_mfma_f32_16x16x32_bf16(af1, bf1, acc[1][1], 0, 0, 0);
        acc[1][2] = __builtin_amdgcn_mfma_f32_16x16x32_bf16(af1, bf2, acc[1][2], 0, 0, 0);
        acc[1][3] = __builtin_amdgcn_mfma_f32_16x16x32_bf16(af1, bf3, acc[1][3], 0, 0, 0);
    }
#pragma unroll
    for (int mi = 0; mi < 2; ++mi) {
        int obase = om0 + wm + mi * 16;         // multiple of 16: Q/K/V uniform
        int oq = obase + quad * 4;              // first of 4 consecutive o
        if (obase < 512) {                      // Q or K: f16x4 [h][t][d0..d0+3]
            int h  = (oq & 255) >> 3;
            int d0 = (quad & 1) * 4;
            _Float16* dst = (obase < 256 ? Qf : Kf);
            float mul = (obase < 256) ? SCALE_LOG2E : 1.0f;
#pragma unroll
            for (int ni = 0; ni < 4; ++ni) {
                int t = t0 + wn + ni * 16 + l15;
                f16x4 o;
#pragma unroll
                for (int r = 0; r < 4; ++r)
                    o[r] = (_Float16)((acc[mi][ni][r] + bias[oq + r]) * mul);
                *(f16x4*)&dst[(((size_t)(n * 32 + h)) * HW + t) * 8 + d0] = o;
            }
        } else {                                // V: bf16 [c][t] scalar stores
            int cv = oq - 512;
#pragma unroll
            for (int ni = 0; ni < 4; ++ni) {
                int t = t0 + wn + ni * 16 + l15;
#pragma unroll
                for (int r = 0; r < 4; ++r)
                    Vbf[((size_t)(n * 256 + cv + r)) * HW + t] =
                        (__bf16)(acc[mi][ni][r] + bias[oq + r]);
            }
        }
    }
}

// ---- out GEMM, LDS-free: 64x64 tile, 4 waves of 32x32 ----------------------
__global__ __launch_bounds__(256) void gemm_out_kernel(
    const __bf16* __restrict__ W, const __bf16* __restrict__ Ball,
    const float* __restrict__ bias, float* __restrict__ Call,
    const float* __restrict__ Rall)
{
    int n = blockIdx.z;
    const __bf16* B = Ball + (size_t)n * HW * C;
    float* Cp = Call + (size_t)n * C * HW;
    const float* R = Rall + (size_t)n * C * HW;
    int om0 = blockIdx.y * 64, t0 = blockIdx.x * 64;
    int tid = threadIdx.x, lane = tid & 63, wave = tid >> 6;
    int l15 = lane & 15, quad = lane >> 4;
    int wm = (wave & 1) * 32, wn = (wave >> 1) * 32;
    const __bf16* ap0 = &W[(size_t)(om0 + wm + l15) * C + quad * 8];
    const __bf16* ap1 = ap0 + (size_t)16 * C;
    const __bf16* bp0 = &B[(size_t)(t0 + wn + l15) * C + quad * 8];
    const __bf16* bp1 = bp0 + (size_t)16 * C;
    floatx4 acc[2][2] = {};
#pragma unroll
    for (int k = 0; k < 8; ++k) {
        int c0 = k * 32;
        bf16x8 af0 = *(const bf16x8*)&ap0[c0];
        bf16x8 af1 = *(const bf16x8*)&ap1[c0];
        bf16x8 bf0 = *(const bf16x8*)&bp0[c0];
        bf16x8 bf1 = *(const bf16x8*)&bp1[c0];
        acc[0][0] = __builtin_amdgcn_mfma_f32_16x16x32_bf16(af0, bf0, acc[0][0], 0, 0, 0);
        acc[0][1] = __builtin_amdgcn_mfma_f32_16x16x32_bf16(af0, bf1, acc[0][1], 0, 0, 0);
        acc[1][0] = __builtin_amdgcn_mfma_f32_16x16x32_bf16(af1, bf0, acc[1][0], 0, 0, 0);
        acc[1][1] = __builtin_amdgcn_mfma_f32_16x16x32_bf16(af1, bf1, acc[1][1], 0, 0, 0);
    }
#pragma unroll
    for (int mi = 0; mi < 2; ++mi) {
#pragma unroll
        for (int r = 0; r < 4; ++r) {
            int o = om0 + wm + mi * 16 + quad * 4 + r;
            float bb = bias[o];
#pragma unroll
            for (int ni = 0; ni < 2; ++ni) {
                int t = t0 + wn + ni * 16 + l15;
                Cp[(size_t)o * HW + t] = acc[mi][ni][r] + bb + R[(size_t)o * HW + t];
            }
        }
    }
}

// ---- MFMA attention, permuted-k PV: 1024 blocks = (n,h,quarter)  [R10] -----
// S^T = mfma_32x32x16_f16(A=K, B=Q). C-layout: col=tq=l31, row=tk=
// (r&3)+8(r>>2)+4*lhi. PV contracts over a PERMUTED k: slot (lhi,j) ->
// tk=(j&3)+8(j>>2)+4lhi, so B-frag = cvt(S^T regs 0..7 / 8..15) verbatim and
// A-frag = V columns {4lhi, 8+4lhi, 16+4lhi, 24+4lhi} (4x ds_read_b64).
// V rows: 0-7 = V dims, 8 = ones => Y^T row 8 = softmax denom. No exchanges.
__global__ __launch_bounds__(256, 4) void attn_kernel(
    const _Float16* __restrict__ Qf, const _Float16* __restrict__ Kf,
    const __bf16* __restrict__ Vg, __bf16* __restrict__ yT)
{
    int quarter = blockIdx.x & 3, h = (blockIdx.x >> 2) & 31, n = blockIdx.x >> 7;
    __shared__ alignas(16) _Float16 Kb[HW][8];        // 16 KB
    __shared__ alignas(16) __bf16   Vb[9][HW + 8];    // ~18.1 KB, stride 1032
    int tid = threadIdx.x;
    const _Float16* kg = Kf + ((size_t)(n * 32 + h)) * HW * 8;
    const __bf16*   vg = Vg + ((size_t)(n * 256 + h * 8)) * HW;
#pragma unroll
    for (int i = 0; i < 4; ++i) {
        int row = tid + i * 256;
        *(f16x8*)&Kb[row][0] = *(const f16x8*)&kg[(size_t)row * 8];
    }
#pragma unroll
    for (int i = 0; i < 4; ++i) {
        int id = tid + i * 256;
        int d = id >> 7, t8 = (id & 127) * 8;
        *(bf16x8*)&Vb[d][t8] = *(const bf16x8*)&vg[(size_t)d * HW + t8];
    }
    if (tid < 128) {
        __bf16 one = (__bf16)1.0f;
        bf16x8 ones = { one, one, one, one, one, one, one, one };
        *(bf16x8*)&Vb[8][tid * 8] = ones;
    }
    int lane = tid & 63, wave = tid >> 6;
    int l31 = lane & 31, lhi = lane >> 5;
    int vrow = l31 < 9 ? l31 : (l31 & 7);       // rows >8 garbage-tolerant
    const __bf16* vbase = &Vb[vrow][0];
    int tqb = quarter * 256 + wave * 64;
    const _Float16* qg = Qf + ((size_t)(n * 32 + h)) * HW * 8;
    f16x8 qf[2];
#pragma unroll
    for (int tau = 0; tau < 2; ++tau) {
        f16x8 qv = { 0, 0, 0, 0, 0, 0, 0, 0 };
        if (lhi == 0)
            qv = *(const f16x8*)&qg[(size_t)(tqb + tau * 32 + l31) * 8];
        qf[tau] = qv;
    }
    __syncthreads();
    floatx16 accG[2] = {};
    floatx16 zero16 = {};
    for (int tkt = 0; tkt < 32; ++tkt) {
        f16x8 kf = *(const f16x8*)&Kb[tkt * 32 + l31][0];
        int cb = tkt * 32 + lhi * 4;
        bf16x4 va0 = *(const bf16x4*)&vbase[cb];
        bf16x4 va1 = *(const bf16x4*)&vbase[cb + 8];
        bf16x4 va2 = *(const bf16x4*)&vbase[cb + 16];
        bf16x4 va3 = *(const bf16x4*)&vbase[cb + 24];
        bf16x8 vf0 = __builtin_shufflevector(va0, va1, 0, 1, 2, 3, 4, 5, 6, 7);
        bf16x8 vf1 = __builtin_shufflevector(va2, va3, 0, 1, 2, 3, 4, 5, 6, 7);
#pragma unroll
        for (int tau = 0; tau < 2; ++tau) {
            floatx16 sT = __builtin_amdgcn_mfma_f32_32x32x16_f16(
                kf, qf[tau], zero16, 0, 0, 0);
            __bf16 p[16];
#pragma unroll
            for (int r = 0; r < 16; ++r) p[r] = (__bf16)EXP2F(sT[r]);
            bf16x8 P0 = { p[0], p[1], p[2], p[3], p[4], p[5], p[6], p[7] };
            bf16x8 P1 = { p[8], p[9], p[10], p[11], p[12], p[13], p[14], p[15] };
            accG[tau] = __builtin_amdgcn_mfma_f32_32x32x16_bf16(
                vf0, P0, accG[tau], 0, 0, 0);
            accG[tau] = __builtin_amdgcn_mfma_f32_32x32x16_bf16(
                vf1, P1, accG[tau], 0, 0, 0);
        }
    }
    // epilogue: Y^T col=tq=l31; rows: lhi=0 regs0-3 = d0-3, reg4 = denom(row 8);
    // lhi=1 regs0-3 = d4-7. Share denom via lane^32.
    __bf16* yp = yT + (size_t)n * HW * C + h * HDIM + lhi * 4;
#pragma unroll
    for (int tau = 0; tau < 2; ++tau) {
        float own4 = accG[tau][4];
        float part4 = __shfl_xor(own4, 32);
        float lsum = lhi ? part4 : own4;
        float inv = 1.0f / lsum;
        bf16x4 o = { (__bf16)(accG[tau][0] * inv), (__bf16)(accG[tau][1] * inv),
                     (__bf16)(accG[tau][2] * inv), (__bf16)(accG[tau][3] * inv) };
        *(bf16x4*)&yp[(size_t)(tqb + tau * 32 + l31) * C] = o;
    }
}

// ---------------------------------------------------------------------------
extern "C" void kernel_launch(void* const* d_in, const int* in_sizes, int n_in,
                              void* d_out, int out_size, void* d_ws, size_t ws_size,
                              hipStream_t stream)
{
    const float* x     = (const float*)d_in[0];
    const float* gn_w  = (const float*)d_in[1];
    const float* gn_b  = (const float*)d_in[2];
    const float* qkv_w = (const float*)d_in[3];
    const float* qkv_b = (const float*)d_in[4];
    const float* out_w = (const float*)d_in[5];
    const float* out_b = (const float*)d_in[6];
    float* out = (float*)d_out;

    char* wsb = (char*)d_ws;
    __bf16*   xnT = (__bf16*)wsb;                         // 4 MB
    _Float16* Qf  = (_Float16*)(wsb + ((size_t)4 << 20));  // 4 MB
    _Float16* Kf  = (_Float16*)(wsb + ((size_t)8 << 20));  // 4 MB
    __bf16*   Vbf = (__bf16*)(wsb + ((size_t)12 << 20));   // 4 MB
    __bf16*   yTp = (__bf16*)(wsb + ((size_t)16 << 20));   // 4 MB
    __bf16*   wq  = (__bf16*)(wsb + ((size_t)20 << 20));   // 384 KB
    __bf16*   wo  = wq + (size_t)3 * C * C;                // 128 KB
    float*    st  = (float*)(wsb + ((size_t)21 << 20));    // 4 KB stats

    gn_stats_cvt_kernel<<<768, 256, 0, stream>>>(x, st, qkv_w, out_w, wq, wo);
    gn_apply_kernel<<<256, 256, 0, stream>>>(x, gn_w, gn_b, st, xnT);
    gemm_qkv_kernel<<<dim3(8, 12, 8), 256, 0, stream>>>(wq, xnT, qkv_b,
                                                        Qf, Kf, Vbf);
    attn_kernel<<<1024, 256, 0, stream>>>(Qf, Kf, Vbf, yTp);
    gemm_out_kernel<<<dim3(16, 4, 8), 256, 0, stream>>>(wo, yTp, out_b, out, x);
}

// Round 14
// 125.328 us; speedup vs baseline: 1.1002x; 1.1002x over previous
//
#include <hip/hip_runtime.h>
#include <hip/hip_bf16.h>
#include <math.h>

// ---------------------------------------------------------------------------
// SelfAttention2d: x(8,256,32,32) -> GN(8 groups) -> qkv(768x256 GEMM)
//   -> 32 heads, d=8, attention over t=1024 -> out(256x256 GEMM) + bias + x
// Round 14: exact R10 revert (measured best, 125.4 us) + unrolled GEMM k-loops
// (software-pipeline global loads across the barrier pair). R9/R11/R13 lesson:
// LDS staging is load-bearing here (L1-overflow / scatter otherwise).
// ---------------------------------------------------------------------------

#define NBATCH 8
#define C 256
#define HW 1024
#define NHEAD 32
#define HDIM 8

typedef __bf16 bf16x8 __attribute__((ext_vector_type(8)));
typedef __bf16 bf16x4 __attribute__((ext_vector_type(4)));
typedef _Float16 f16x8 __attribute__((ext_vector_type(8)));
typedef _Float16 f16x4 __attribute__((ext_vector_type(4)));
typedef float floatx4 __attribute__((ext_vector_type(4)));
typedef float floatx16 __attribute__((ext_vector_type(16)));

#if __has_builtin(__builtin_amdgcn_exp2f)
#define EXP2F(x) __builtin_amdgcn_exp2f(x)
#else
#define EXP2F(x) exp2f(x)
#endif

#define SCALE_LOG2E 0.51013249662f   // (1/sqrt(8)) * log2(e)

// ---- GN stats (blocks 0..511) + weight cvt (blocks 512..767) ---------------
__global__ __launch_bounds__(256) void gn_stats_cvt_kernel(
    const float* __restrict__ x, float* __restrict__ stats,
    const float* __restrict__ qw, const float* __restrict__ ow,
    __bf16* __restrict__ wq, __bf16* __restrict__ wo)
{
    int blk = blockIdx.x;
    int tid = threadIdx.x;
    if (blk >= 512) {                            // weight convert
        int id = (blk - 512) * 256 + tid;        // 0..65535, 4 floats each
        float4 v;
        __bf16* dst;
        if (id < 49152) { v = *(const float4*)&qw[id * 4]; dst = wq + id * 4; }
        else { v = *(const float4*)&ow[(id - 49152) * 4]; dst = wo + (id - 49152) * 4; }
        bf16x4 o = { (__bf16)v.x, (__bf16)v.y, (__bf16)v.z, (__bf16)v.w };
        *(bf16x4*)dst = o;
        return;
    }
    int part = blk & 7, ng = blk >> 3;
    const float4* xv = (const float4*)(x + ((size_t)ng * 32 + part * 4) * HW);
    float s = 0.f, ss = 0.f;
#pragma unroll
    for (int i = 0; i < 4; ++i) {
        float4 v = xv[tid + i * 256];
        s  += v.x + v.y + v.z + v.w;
        ss += v.x*v.x + v.y*v.y + v.z*v.z + v.w*v.w;
    }
#pragma unroll
    for (int o = 32; o; o >>= 1) { s += __shfl_xor(s, o); ss += __shfl_xor(ss, o); }
    __shared__ float rs[4], rss[4];
    int wave = tid >> 6, lane = tid & 63;
    if (lane == 0) { rs[wave] = s; rss[wave] = ss; }
    __syncthreads();
    if (tid == 0) {
        stats[blk * 2]     = rs[0] + rs[1] + rs[2] + rs[3];
        stats[blk * 2 + 1] = rss[0] + rss[1] + rss[2] + rss[3];
    }
}

// ---- GN apply -> xnT bf16 [n][t][c]: 256 blocks = (n,g,chunk of 256 t) -----
__global__ __launch_bounds__(256) void gn_apply_kernel(
    const float* __restrict__ x, const float* __restrict__ w,
    const float* __restrict__ b, const float* __restrict__ stats,
    __bf16* __restrict__ xnT)
{
    int blk = blockIdx.x;
    int chunk = blk & 3, ng = blk >> 2;
    int n = ng >> 3, g = ng & 7;
    float s = 0.f, ss = 0.f;
#pragma unroll
    for (int p = 0; p < 8; ++p) {            // uniform -> scalar loads
        s  += stats[(ng * 8 + p) * 2];
        ss += stats[(ng * 8 + p) * 2 + 1];
    }
    const float invN = 1.0f / 32768.0f;
    float mean = s * invN;
    float var  = ss * invN - mean * mean;
    float rstd = rsqrtf(var + 1e-5f);
    const float* xp = x + ((size_t)ng * 32) * HW;
    int tid = threadIdx.x, t0 = chunk * 256;
    __shared__ __bf16 Lt[32][257];
#pragma unroll 8
    for (int c = 0; c < 32; ++c) {
        float wc = w[g * 32 + c] * rstd;
        float bc = b[g * 32 + c] - mean * wc;
        float v = xp[(size_t)c * HW + t0 + tid];
        Lt[c][tid] = (__bf16)(v * wc + bc);
    }
    __syncthreads();
    __bf16* xo = xnT + (size_t)n * HW * C + g * 32;
#pragma unroll
    for (int q = 0; q < 4; ++q) {
        bf16x8 o;
#pragma unroll
        for (int e = 0; e < 8; ++e) o[e] = Lt[q * 8 + e][tid];
        *(bf16x8*)&xo[(size_t)(t0 + tid) * C + q * 8] = o;
    }
}

// ---- qkv GEMM: 64x128 tile, 4 waves of 32x64; scatter epilogue -------------
// A = qkv_w bf16 [o][c]; B = xnT bf16 [t][c]. Outputs:
//   o<256  -> Qf f16 [n][h][t][8], value*(scale*log2e)
//   o<512  -> Kf f16 [n][h][t][8]
//   else   -> Vb bf16 [n][o-512][t]  (d-major)
// k-loop fully unrolled: compiler clusters next-iter global loads for latency
// hiding while keeping the (measured-necessary) LDS staging.
__global__ __launch_bounds__(256) void gemm_qkv_kernel(
    const __bf16* __restrict__ W, const __bf16* __restrict__ Ball,
    const float* __restrict__ bias, _Float16* __restrict__ Qf,
    _Float16* __restrict__ Kf, __bf16* __restrict__ Vbf)
{
    int n = blockIdx.z;
    const __bf16* B = Ball + (size_t)n * HW * C;
    int om0 = blockIdx.y * 64, t0 = blockIdx.x * 128;
    __shared__ __bf16 As[64 * 32];
    __shared__ __bf16 Bs[128 * 32];
    int tid = threadIdx.x, lane = tid & 63, wave = tid >> 6;
    int l15 = lane & 15, quad = lane >> 4;
    int wm = (wave & 1) * 32, wn = (wave >> 1) * 64;
    int swq = (quad ^ (l15 & 3)) * 8;
    int arow = tid >> 2, aq = tid & 3;
    int sw = (aq ^ (arow & 3)) * 8;
    floatx4 acc[2][4] = {};
#pragma unroll
    for (int k = 0; k < 8; ++k) {
        int c0 = k * 32;
        bf16x8 av  = *(const bf16x8*)&W[(size_t)(om0 + arow) * C + c0 + aq * 8];
        bf16x8 bv0 = *(const bf16x8*)&B[(size_t)(t0 + arow) * C + c0 + aq * 8];
        bf16x8 bv1 = *(const bf16x8*)&B[(size_t)(t0 + 64 + arow) * C + c0 + aq * 8];
        __syncthreads();
        *(bf16x8*)&As[arow * 32 + sw] = av;
        *(bf16x8*)&Bs[arow * 32 + sw] = bv0;
        *(bf16x8*)&Bs[(arow + 64) * 32 + sw] = bv1;   // (arow+64)&3 == arow&3
        __syncthreads();
        bf16x8 af[2], bfr[4];
#pragma unroll
        for (int mi = 0; mi < 2; ++mi)
            af[mi] = *(const bf16x8*)&As[(wm + mi * 16 + l15) * 32 + swq];
#pragma unroll
        for (int ni = 0; ni < 4; ++ni)
            bfr[ni] = *(const bf16x8*)&Bs[(wn + ni * 16 + l15) * 32 + swq];
#pragma unroll
        for (int mi = 0; mi < 2; ++mi)
#pragma unroll
            for (int ni = 0; ni < 4; ++ni)
                acc[mi][ni] = __builtin_amdgcn_mfma_f32_16x16x32_bf16(
                    af[mi], bfr[ni], acc[mi][ni], 0, 0, 0);
    }
#pragma unroll
    for (int mi = 0; mi < 2; ++mi) {
        int obase = om0 + wm + mi * 16;         // multiple of 16: Q/K/V uniform
        int oq = obase + quad * 4;              // first of 4 consecutive o
        if (obase < 512) {                      // Q or K: f16x4 [h][t][d0..d0+3]
            int h  = (oq & 255) >> 3;
            int d0 = (quad & 1) * 4;
            _Float16* dst = (obase < 256 ? Qf : Kf);
            float mul = (obase < 256) ? SCALE_LOG2E : 1.0f;
#pragma unroll
            for (int ni = 0; ni < 4; ++ni) {
                int t = t0 + wn + ni * 16 + l15;
                f16x4 o;
#pragma unroll
                for (int r = 0; r < 4; ++r)
                    o[r] = (_Float16)((acc[mi][ni][r] + bias[oq + r]) * mul);
                *(f16x4*)&dst[(((size_t)(n * 32 + h)) * HW + t) * 8 + d0] = o;
            }
        } else {                                // V: bf16 [c][t] scalar stores
            int cv = oq - 512;
#pragma unroll
            for (int ni = 0; ni < 4; ++ni) {
                int t = t0 + wn + ni * 16 + l15;
#pragma unroll
                for (int r = 0; r < 4; ++r)
                    Vbf[((size_t)(n * 256 + cv + r)) * HW + t] =
                        (__bf16)(acc[mi][ni][r] + bias[oq + r]);
            }
        }
    }
}

// ---- out GEMM: 64x64 tile, 4 waves of 32x32; f32 + bias + residual ---------
__global__ __launch_bounds__(256) void gemm_out_kernel(
    const __bf16* __restrict__ W, const __bf16* __restrict__ Ball,
    const float* __restrict__ bias, float* __restrict__ Call,
    const float* __restrict__ Rall)
{
    int n = blockIdx.z;
    const __bf16* B = Ball + (size_t)n * HW * C;
    float* Cp = Call + (size_t)n * C * HW;
    const float* R = Rall + (size_t)n * C * HW;
    int om0 = blockIdx.y * 64, t0 = blockIdx.x * 64;
    __shared__ __bf16 As[64 * 32];
    __shared__ __bf16 Bs[64 * 32];
    int tid = threadIdx.x, lane = tid & 63, wave = tid >> 6;
    int l15 = lane & 15, quad = lane >> 4;
    int wm = (wave & 1) * 32, wn = (wave >> 1) * 32;
    int swq = (quad ^ (l15 & 3)) * 8;
    int arow = tid >> 2, aq = tid & 3;
    int sw = (aq ^ (arow & 3)) * 8;
    floatx4 acc[2][2] = {};
#pragma unroll
    for (int k = 0; k < 8; ++k) {
        int c0 = k * 32;
        bf16x8 av = *(const bf16x8*)&W[(size_t)(om0 + arow) * C + c0 + aq * 8];
        bf16x8 bv = *(const bf16x8*)&B[(size_t)(t0 + arow) * C + c0 + aq * 8];
        __syncthreads();
        *(bf16x8*)&As[arow * 32 + sw] = av;
        *(bf16x8*)&Bs[arow * 32 + sw] = bv;
        __syncthreads();
        bf16x8 af[2], bfr[2];
#pragma unroll
        for (int mi = 0; mi < 2; ++mi)
            af[mi] = *(const bf16x8*)&As[(wm + mi * 16 + l15) * 32 + swq];
#pragma unroll
        for (int ni = 0; ni < 2; ++ni)
            bfr[ni] = *(const bf16x8*)&Bs[(wn + ni * 16 + l15) * 32 + swq];
#pragma unroll
        for (int mi = 0; mi < 2; ++mi)
#pragma unroll
            for (int ni = 0; ni < 2; ++ni)
                acc[mi][ni] = __builtin_amdgcn_mfma_f32_16x16x32_bf16(
                    af[mi], bfr[ni], acc[mi][ni], 0, 0, 0);
    }
#pragma unroll
    for (int mi = 0; mi < 2; ++mi) {
#pragma unroll
        for (int r = 0; r < 4; ++r) {
            int o = om0 + wm + mi * 16 + quad * 4 + r;
            float bb = bias[o];
#pragma unroll
            for (int ni = 0; ni < 2; ++ni) {
                int t = t0 + wn + ni * 16 + l15;
                Cp[(size_t)o * HW + t] = acc[mi][ni][r] + bb + R[(size_t)o * HW + t];
            }
        }
    }
}

// ---- MFMA attention, permuted-k PV: 1024 blocks = (n,h,quarter)  [R10] -----
// S^T = mfma_32x32x16_f16(A=K, B=Q). C-layout: col=tq=l31, row=tk=
// (r&3)+8(r>>2)+4*lhi. PV contracts over a PERMUTED k: slot (lhi,j) ->
// tk=(j&3)+8(j>>2)+4lhi, so B-frag = cvt(S^T regs 0..7 / 8..15) verbatim and
// A-frag = V columns {4lhi, 8+4lhi, 16+4lhi, 24+4lhi} (4x ds_read_b64).
// V rows: 0-7 = V dims, 8 = ones => Y^T row 8 = softmax denom. No exchanges.
__global__ __launch_bounds__(256, 4) void attn_kernel(
    const _Float16* __restrict__ Qf, const _Float16* __restrict__ Kf,
    const __bf16* __restrict__ Vg, __bf16* __restrict__ yT)
{
    int quarter = blockIdx.x & 3, h = (blockIdx.x >> 2) & 31, n = blockIdx.x >> 7;
    __shared__ alignas(16) _Float16 Kb[HW][8];        // 16 KB
    __shared__ alignas(16) __bf16   Vb[9][HW + 8];    // ~18.1 KB, stride 1032
    int tid = threadIdx.x;
    const _Float16* kg = Kf + ((size_t)(n * 32 + h)) * HW * 8;
    const __bf16*   vg = Vg + ((size_t)(n * 256 + h * 8)) * HW;
#pragma unroll
    for (int i = 0; i < 4; ++i) {
        int row = tid + i * 256;
        *(f16x8*)&Kb[row][0] = *(const f16x8*)&kg[(size_t)row * 8];
    }
#pragma unroll
    for (int i = 0; i < 4; ++i) {
        int id = tid + i * 256;
        int d = id >> 7, t8 = (id & 127) * 8;
        *(bf16x8*)&Vb[d][t8] = *(const bf16x8*)&vg[(size_t)d * HW + t8];
    }
    if (tid < 128) {
        __bf16 one = (__bf16)1.0f;
        bf16x8 ones = { one, one, one, one, one, one, one, one };
        *(bf16x8*)&Vb[8][tid * 8] = ones;
    }
    int lane = tid & 63, wave = tid >> 6;
    int l31 = lane & 31, lhi = lane >> 5;
    int vrow = l31 < 9 ? l31 : (l31 & 7);       // rows >8 garbage-tolerant
    const __bf16* vbase = &Vb[vrow][0];
    int tqb = quarter * 256 + wave * 64;
    const _Float16* qg = Qf + ((size_t)(n * 32 + h)) * HW * 8;
    f16x8 qf[2];
#pragma unroll
    for (int tau = 0; tau < 2; ++tau) {
        f16x8 qv = { 0, 0, 0, 0, 0, 0, 0, 0 };
        if (lhi == 0)
            qv = *(const f16x8*)&qg[(size_t)(tqb + tau * 32 + l31) * 8];
        qf[tau] = qv;
    }
    __syncthreads();
    floatx16 accG[2] = {};
    floatx16 zero16 = {};
    for (int tkt = 0; tkt < 32; ++tkt) {
        f16x8 kf = *(const f16x8*)&Kb[tkt * 32 + l31][0];
        int cb = tkt * 32 + lhi * 4;
        bf16x4 va0 = *(const bf16x4*)&vbase[cb];
        bf16x4 va1 = *(const bf16x4*)&vbase[cb + 8];
        bf16x4 va2 = *(const bf16x4*)&vbase[cb + 16];
        bf16x4 va3 = *(const bf16x4*)&vbase[cb + 24];
        bf16x8 vf0 = __builtin_shufflevector(va0, va1, 0, 1, 2, 3, 4, 5, 6, 7);
        bf16x8 vf1 = __builtin_shufflevector(va2, va3, 0, 1, 2, 3, 4, 5, 6, 7);
#pragma unroll
        for (int tau = 0; tau < 2; ++tau) {
            floatx16 sT = __builtin_amdgcn_mfma_f32_32x32x16_f16(
                kf, qf[tau], zero16, 0, 0, 0);
            __bf16 p[16];
#pragma unroll
            for (int r = 0; r < 16; ++r) p[r] = (__bf16)EXP2F(sT[r]);
            bf16x8 P0 = { p[0], p[1], p[2], p[3], p[4], p[5], p[6], p[7] };
            bf16x8 P1 = { p[8], p[9], p[10], p[11], p[12], p[13], p[14], p[15] };
            accG[tau] = __builtin_amdgcn_mfma_f32_32x32x16_bf16(
                vf0, P0, accG[tau], 0, 0, 0);
            accG[tau] = __builtin_amdgcn_mfma_f32_32x32x16_bf16(
                vf1, P1, accG[tau], 0, 0, 0);
        }
    }
    // epilogue: Y^T col=tq=l31; rows: lhi=0 regs0-3 = d0-3, reg4 = denom(row 8);
    // lhi=1 regs0-3 = d4-7. Share denom via lane^32.
    __bf16* yp = yT + (size_t)n * HW * C + h * HDIM + lhi * 4;
#pragma unroll
    for (int tau = 0; tau < 2; ++tau) {
        float own4 = accG[tau][4];
        float part4 = __shfl_xor(own4, 32);
        float lsum = lhi ? part4 : own4;
        float inv = 1.0f / lsum;
        bf16x4 o = { (__bf16)(accG[tau][0] * inv), (__bf16)(accG[tau][1] * inv),
                     (__bf16)(accG[tau][2] * inv), (__bf16)(accG[tau][3] * inv) };
        *(bf16x4*)&yp[(size_t)(tqb + tau * 32 + l31) * C] = o;
    }
}

// ---------------------------------------------------------------------------
extern "C" void kernel_launch(void* const* d_in, const int* in_sizes, int n_in,
                              void* d_out, int out_size, void* d_ws, size_t ws_size,
                              hipStream_t stream)
{
    const float* x     = (const float*)d_in[0];
    const float* gn_w  = (const float*)d_in[1];
    const float* gn_b  = (const float*)d_in[2];
    const float* qkv_w = (const float*)d_in[3];
    const float* qkv_b = (const float*)d_in[4];
    const float* out_w = (const float*)d_in[5];
    const float* out_b = (const float*)d_in[6];
    float* out = (float*)d_out;

    char* wsb = (char*)d_ws;
    __bf16*   xnT = (__bf16*)wsb;                         // 4 MB
    _Float16* Qf  = (_Float16*)(wsb + ((size_t)4 << 20));  // 4 MB
    _Float16* Kf  = (_Float16*)(wsb + ((size_t)8 << 20));  // 4 MB
    __bf16*   Vbf = (__bf16*)(wsb + ((size_t)12 << 20));   // 4 MB
    __bf16*   yTp = (__bf16*)(wsb + ((size_t)16 << 20));   // 4 MB
    __bf16*   wq  = (__bf16*)(wsb + ((size_t)20 << 20));   // 384 KB
    __bf16*   wo  = wq + (size_t)3 * C * C;                // 128 KB
    float*    st  = (float*)(wsb + ((size_t)21 << 20));    // 4 KB stats

    gn_stats_cvt_kernel<<<768, 256, 0, stream>>>(x, st, qkv_w, out_w, wq, wo);
    gn_apply_kernel<<<256, 256, 0, stream>>>(x, gn_w, gn_b, st, xnT);
    gemm_qkv_kernel<<<dim3(8, 12, 8), 256, 0, stream>>>(wq, xnT, qkv_b,
                                                        Qf, Kf, Vbf);
    attn_kernel<<<1024, 256, 0, stream>>>(Qf, Kf, Vbf, yTp);
    gemm_out_kernel<<<dim3(16, 4, 8), 256, 0, stream>>>(wo, yTp, out_b, out, x);
}